// Round 14
// baseline (1616.488 us; speedup 1.0000x reference)
//
#include <hip/hip_runtime.h>
#include <hip/hip_bf16.h>

constexpr int HID = 256;
constexpr int NS = 7, NC = 2, NF = 9, HS = 50;
constexpr int BT  = 32;    // batch rows per block
constexpr int ROW = 264;   // bf16 row pitch for h buffers / w3t (528 B)
constexpr int NIP = 40;    // ni_bf row pitch in shorts (80 B, 16B-aligned)
constexpr float DT_C = 0.02f;

using short8 = __attribute__((ext_vector_type(8))) short;
using f32x4  = __attribute__((ext_vector_type(4))) float;

__device__ __forceinline__ unsigned short f2bf(float f) {
    unsigned int u = __float_as_uint(f);
    return (unsigned short)((u + 0x7FFFu + ((u >> 16) & 1u)) >> 16);   // RNE
}
__device__ __forceinline__ unsigned int pk2(float lo, float hi) {
    __hip_bfloat162 h = __float22bfloat162_rn(make_float2(lo, hi));
    return *reinterpret_cast<unsigned int*>(&h);
}
__device__ __forceinline__ float fast_tanh(float x) {
    // tanh(x) = 1 - 2/(e^{2x}+1); v_rcp_f32 forced via builtin (no IEEE div seq).
    float e = __expf(2.0f * x);
    return fmaf(-2.0f, __builtin_amdgcn_rcpf(e + 1.0f), 1.0f);
}

// 16 waves/block, wave owns 16 cols (w2f = 32 VGPR). Register diet vs r13
// (which spilled at the 64-reg/8-wave tier): separate hA/hB (no pkv, no S2a
// barrier), sequential bt passes (single acc), DT*b3 in LDS, unroll-2 kb loop
// (caps transient hv regs). Target total <= 64 -> 8 waves/SIMD, 2 blocks/CU,
// grid 1024 = 2*256*2 rounds exactly.
__global__ __launch_bounds__(1024, 8)
void rollout_mfma10(const float* __restrict__ x,
                    const float* __restrict__ W1, const float* __restrict__ b1,
                    const float* __restrict__ W2, const float* __restrict__ b2,
                    const float* __restrict__ W3, const float* __restrict__ b3,
                    float* __restrict__ out)
{
    __shared__ __align__(16) unsigned short hA[BT][ROW];    // h1
    __shared__ __align__(16) unsigned short hB[BT][ROW];    // h2
    __shared__ __align__(16) unsigned short w3t[16][ROW];   // W3^T, cols>=7 zero
    __shared__ __align__(16) unsigned short nibf[BT][NIP];  // [u0,u1,s0..6,1.0,0...]
    __shared__ __align__(16) float b2s[HID];
    __shared__ __align__(16) float db3[16];                 // DT*b3, s>=7 zero

    const int tid  = threadIdx.x;
    const int w    = tid >> 6;        // wave 0..15, owns cols [w*16, w*16+16)
    const int lane = tid & 63;
    const int l15  = lane & 15;
    const int lg   = lane >> 4;
    const int b0   = blockIdx.x * BT;

    // ---- one-time: W2^T A-fragments (k = kb*32+lg*8+j, n = w*16+l15) ----
    short8 w2f[8];
    {
        const int n = w * 16 + l15;
        #pragma unroll
        for (int kb = 0; kb < 8; ++kb)
            #pragma unroll
            for (int j = 0; j < 8; ++j)
                w2f[kb][j] = (short)f2bf(W2[(kb * 32 + lg * 8 + j) * HID + n]);
    }
    // W1' A-fragment: rows 0..8 = W1, row 9 = b1 (bias via k), rows 10..31 = 0
    short8 w1f;
    {
        const int n = w * 16 + l15;
        #pragma unroll
        for (int j = 0; j < 8; ++j) {
            const int k = lg * 8 + j;
            float v = (k < NF) ? W1[k * HID + n] : (k == NF ? b1[n] : 0.0f);
            w1f[j] = (short)f2bf(v);
        }
    }
    for (int i = tid; i < HID; i += 1024) b2s[i] = b2[i];
    if (tid < 16) db3[tid] = (tid < NS) ? DT_C * b3[tid] : 0.0f;
    for (int i = tid; i < 16 * HID; i += 1024) {
        const int s = i & 15, k = i >> 4;
        w3t[s][k] = (s < NS) ? f2bf(W3[k * NS + s]) : (unsigned short)0;
    }
    // net-in rows: x[b][0][0..8], bias-one at k=9, zeros above
    if (tid < BT) {
        const float* xp = &x[(b0 + tid) * (HS * NF)];
        #pragma unroll
        for (int k = 0; k < NIP; ++k) nibf[tid][k] = 0;
        #pragma unroll
        for (int f = 0; f < NF; ++f) nibf[tid][f] = f2bf(xp[f]);
        nibf[tid][NF] = f2bf(1.0f);
    }
    // master state in registers of waves 0,1: lane (l15,lg) owns b=w*16+l15, s=lg*4+r
    float st[4] = {0.f, 0.f, 0.f, 0.f};
    if (w < 2) {
        const int b = w * 16 + l15;
        #pragma unroll
        for (int r = 0; r < 4; ++r) {
            const int s = lg * 4 + r;
            if (s < NS) st[r] = x[(b0 + b) * (HS * NF) + NC + s];
        }
    }
    __syncthreads();

    for (int t = 0; t < HS; ++t) {
        // ---------- P1: h1 = tanh([ni,1] @ W1') via MFMA (sequential bt) ----------
        #pragma unroll
        for (int bt = 0; bt < 2; ++bt) {
            f32x4 a1 = {0.f, 0.f, 0.f, 0.f};
            short8 nf = *reinterpret_cast<const short8*>(&nibf[bt * 16 + l15][lg * 8]);
            a1 = __builtin_amdgcn_mfma_f32_16x16x32_bf16(w1f, nf, a1, 0, 0, 0);
            uint2 pk;
            pk.x = pk2(fast_tanh(a1[0]), fast_tanh(a1[1]));
            pk.y = pk2(fast_tanh(a1[2]), fast_tanh(a1[3]));
            *reinterpret_cast<uint2*>(&hA[bt * 16 + l15][w * 16 + lg * 4]) = pk;
        }
        __syncthreads();   // S1: h1 ready

        // ---------- P2: h2 = tanh(h1 @ W2 + b2) via MFMA (sequential bt) ----------
        #pragma unroll
        for (int bt = 0; bt < 2; ++bt) {
            f32x4 acc;
            {
                const float4 bv = *reinterpret_cast<const float4*>(&b2s[w * 16 + lg * 4]);
                acc[0] = bv.x; acc[1] = bv.y; acc[2] = bv.z; acc[3] = bv.w;
            }
            #pragma unroll 2
            for (int kb = 0; kb < 8; ++kb) {
                short8 hv = *reinterpret_cast<const short8*>(&hA[bt * 16 + l15][kb * 32 + lg * 8]);
                acc = __builtin_amdgcn_mfma_f32_16x16x32_bf16(w2f[kb], hv, acc, 0, 0, 0);
            }
            uint2 pk;
            pk.x = pk2(fast_tanh(acc[0]), fast_tanh(acc[1]));
            pk.y = pk2(fast_tanh(acc[2]), fast_tanh(acc[3]));
            *reinterpret_cast<uint2*>(&hB[bt * 16 + l15][w * 16 + lg * 4]) = pk;
        }
        __syncthreads();   // S2: h2 ready

        // ---------- P3: d = h2 @ W3 + b3; state += DT*d (waves 0,1) ----------
        if (w < 2) {
            f32x4 a3 = {0.f, 0.f, 0.f, 0.f};
            #pragma unroll 2
            for (int kb = 0; kb < 8; ++kb) {
                short8 hv = *reinterpret_cast<const short8*>(&hB[w * 16 + l15][kb * 32 + lg * 8]);
                short8 wf = *reinterpret_cast<const short8*>(&w3t[l15][kb * 32 + lg * 8]);
                a3 = __builtin_amdgcn_mfma_f32_16x16x32_bf16(wf, hv, a3, 0, 0, 0);
            }
            const int b = w * 16 + l15;
            const float4 d3 = *reinterpret_cast<const float4*>(&db3[lg * 4]);
            float nsv[4];
            nsv[0] = st[0] + DT_C * a3[0] + d3.x;
            nsv[1] = st[1] + DT_C * a3[1] + d3.y;
            nsv[2] = st[2] + DT_C * a3[2] + d3.z;
            nsv[3] = st[3] + DT_C * a3[3] + d3.w;
            if (lg == 0) {
                // s = 0..3 -> nibf shorts [2..5]
                st[0] = nsv[0]; st[1] = nsv[1]; st[2] = nsv[2]; st[3] = nsv[3];
                *reinterpret_cast<unsigned int*>(&nibf[b][2]) = pk2(nsv[0], nsv[1]);
                *reinterpret_cast<unsigned int*>(&nibf[b][4]) = pk2(nsv[2], nsv[3]);
                const int obase = (b0 + b) * (HS * NS) + t * NS;
                out[obase + 0] = nsv[0];
                out[obase + 1] = nsv[1];
                out[obase + 2] = nsv[2];
                out[obase + 3] = nsv[3];
            } else if (lg == 1) {
                // s = 4..6 -> nibf shorts [6..8]
                st[0] = nsv[0]; st[1] = nsv[1]; st[2] = nsv[2];
                *reinterpret_cast<unsigned int*>(&nibf[b][6]) = pk2(nsv[0], nsv[1]);
                nibf[b][8] = (unsigned short)pk2(nsv[2], nsv[2]);
                const int obase = (b0 + b) * (HS * NS) + t * NS;
                out[obase + 4] = nsv[0];
                out[obase + 5] = nsv[1];
                out[obase + 6] = nsv[2];
            }
        } else if (w == 2) {
            // next-step controls -> nibf[b][0..1] (bf16)
            if (t + 1 < HS) {
                const int b = lane & 31, c = lane >> 5;
                nibf[b][c] = f2bf(x[(b0 + b) * (HS * NF) + (t + 1) * NF + c]);
            }
        }
        __syncthreads();   // S3: state/controls ready for next P1
    }
}

extern "C" void kernel_launch(void* const* d_in, const int* in_sizes, int n_in,
                              void* d_out, int out_size, void* d_ws, size_t ws_size,
                              hipStream_t stream) {
    const float* x  = (const float*)d_in[0];
    const float* W1 = (const float*)d_in[1];
    const float* b1 = (const float*)d_in[2];
    const float* W2 = (const float*)d_in[3];
    const float* b2 = (const float*)d_in[4];
    const float* W3 = (const float*)d_in[5];
    const float* b3 = (const float*)d_in[6];
    float* out = (float*)d_out;

    const int B = in_sizes[0] / (HS * NF);   // 32768
    dim3 grid(B / BT), block(1024);
    hipLaunchKernelGGL(rollout_mfma10, grid, block, 0, stream,
                       x, W1, b1, W2, b2, W3, b3, out);
}

// Round 16
// 370.153 us; speedup vs baseline: 4.3671x; 4.3671x over previous
//
#include <hip/hip_runtime.h>
#include <hip/hip_bf16.h>

constexpr int HID = 256;
constexpr int NS = 7, NC = 2, NF = 9, HS = 50;
constexpr int BT  = 64;    // batch rows per block: two independent 32-row tiles
constexpr int ROW = 264;   // bf16 row pitch for h buffer / w3t (528 B)
constexpr int NIP = 32;    // ni_bf row pitch in shorts (64 B) == MFMA K exactly
constexpr float DT_C = 0.02f;

using short8 = __attribute__((ext_vector_type(8))) short;
using f32x4  = __attribute__((ext_vector_type(4))) float;

__device__ __forceinline__ unsigned short f2bf(float f) {
    unsigned int u = __float_as_uint(f);
    return (unsigned short)((u + 0x7FFFu + ((u >> 16) & 1u)) >> 16);   // RNE
}
__device__ __forceinline__ unsigned int pk2(float lo, float hi) {
    __hip_bfloat162 h = __float22bfloat162_rn(make_float2(lo, hi));
    return *reinterpret_cast<unsigned int*>(&h);
}
__device__ __forceinline__ float fast_tanh(float x) {
    // tanh(x) = 1 - 2/(e^{2x}+1); v_rcp_f32 forced via builtin (no IEEE div seq).
    float e = __expf(2.0f * x);
    return fmaf(-2.0f, __builtin_amdgcn_rcpf(e + 1.0f), 1.0f);
}

// Two independent 32-batch tiles per block: barriers amortized 2x (4 per
// DOUBLE step), P3 of the two tiles runs on disjoint waves in parallel,
// phases are 2x longer for ILP. Register tier kept at r11's proven
// 4 waves/SIMD (peak est ~122 < 128); W2 register-resident (r12: streaming
// exposes latency; r10/r13/r14: forcing 8 waves spills).
__global__ __launch_bounds__(512, 4)
void rollout_mfma11(const float* __restrict__ x,
                    const float* __restrict__ W1, const float* __restrict__ b1,
                    const float* __restrict__ W2, const float* __restrict__ b2,
                    const float* __restrict__ W3, const float* __restrict__ b3,
                    float* __restrict__ out)
{
    __shared__ __align__(16) unsigned short h[BT][ROW];     // h1, then h2 (both tiles)
    __shared__ __align__(16) unsigned short w3t[16][ROW];   // W3^T, cols>=7 zero
    __shared__ __align__(16) unsigned short nibf[BT][NIP];  // [u0,u1,s0..6,1.0,0..]
    __shared__ __align__(16) float b2s[HID];
    __shared__ __align__(16) float db3[16];                 // DT*b3, s>=7 zero

    const int tid  = threadIdx.x;
    const int w    = tid >> 6;        // wave 0..7, owns cols [w*32, w*32+32)
    const int lane = tid & 63;
    const int l15  = lane & 15;
    const int lg   = lane >> 4;
    const int b0   = blockIdx.x * BT;

    // ---- one-time: W2^T A-fragments (k = kb*32+lg*8+j, n = w*32+q*16+l15) ----
    short8 w2f[2][8];
    #pragma unroll
    for (int q = 0; q < 2; ++q) {
        const int n = w * 32 + q * 16 + l15;
        #pragma unroll
        for (int kb = 0; kb < 8; ++kb)
            #pragma unroll
            for (int j = 0; j < 8; ++j)
                w2f[q][kb][j] = (short)f2bf(W2[(kb * 32 + lg * 8 + j) * HID + n]);
    }
    // W1' A-fragments: rows 0..8 = W1, row 9 = b1 (bias via k), rows 10..31 = 0
    short8 w1f[2];
    #pragma unroll
    for (int q = 0; q < 2; ++q) {
        const int n = w * 32 + q * 16 + l15;
        #pragma unroll
        for (int j = 0; j < 8; ++j) {
            const int k = lg * 8 + j;
            float v = (k < NF) ? W1[k * HID + n] : (k == NF ? b1[n] : 0.0f);
            w1f[q][j] = (short)f2bf(v);
        }
    }
    for (int i = tid; i < HID; i += 512) b2s[i] = b2[i];
    if (tid < 16) db3[tid] = (tid < NS) ? DT_C * b3[tid] : 0.0f;
    for (int i = tid; i < 16 * HID; i += 512) {
        const int s = i & 15, k = i >> 4;
        w3t[s][k] = (s < NS) ? f2bf(W3[k * NS + s]) : (unsigned short)0;
    }
    // net-in rows (both tiles): x[b][0][0..8], bias-one at k=9, zeros above
    if (tid < BT) {
        const float* xp = &x[(b0 + tid) * (HS * NF)];
        #pragma unroll
        for (int k = 0; k < NIP; ++k) nibf[tid][k] = 0;
        #pragma unroll
        for (int f = 0; f < NF; ++f) nibf[tid][f] = f2bf(xp[f]);
        nibf[tid][NF] = f2bf(1.0f);
    }
    // master state: waves 0,1 -> tile A rows, waves 2,3 -> tile B rows.
    // lane (l15) row b = (w>>1)*32 + (w&1)*16 + l15, element s = lg*4+r.
    float st[4] = {0.f, 0.f, 0.f, 0.f};
    if (w < 4) {
        const int b = (w >> 1) * 32 + (w & 1) * 16 + l15;
        #pragma unroll
        for (int r = 0; r < 4; ++r) {
            const int s = lg * 4 + r;
            if (s < NS) st[r] = x[(b0 + b) * (HS * NF) + NC + s];
        }
    }
    __syncthreads();

    for (int t = 0; t < HS; ++t) {
        // ---------- P1: h1 = tanh([ni,1] @ W1'), both tiles ----------
        #pragma unroll
        for (int rt = 0; rt < 4; ++rt) {        // rt = tile*2 + bt: rows rt*16
            f32x4 a1 = {0.f, 0.f, 0.f, 0.f};
            short8 nf = *reinterpret_cast<const short8*>(&nibf[rt * 16 + l15][lg * 8]);
            f32x4 a1b = __builtin_amdgcn_mfma_f32_16x16x32_bf16(w1f[0], nf, a1, 0, 0, 0);
            f32x4 a1c = __builtin_amdgcn_mfma_f32_16x16x32_bf16(w1f[1], nf, a1, 0, 0, 0);
            uint2 pk0, pk1;
            pk0.x = pk2(fast_tanh(a1b[0]), fast_tanh(a1b[1]));
            pk0.y = pk2(fast_tanh(a1b[2]), fast_tanh(a1b[3]));
            pk1.x = pk2(fast_tanh(a1c[0]), fast_tanh(a1c[1]));
            pk1.y = pk2(fast_tanh(a1c[2]), fast_tanh(a1c[3]));
            *reinterpret_cast<uint2*>(&h[rt * 16 + l15][w * 32 + lg * 4]) = pk0;
            *reinterpret_cast<uint2*>(&h[rt * 16 + l15][w * 32 + 16 + lg * 4]) = pk1;
        }
        __syncthreads();   // S1: h1 ready (both tiles)

        // ---------- P2: h2 = tanh(h1 @ W2 + b2), tile A then tile B ----------
        uint2 pkvA[4], pkvB[4];     // [q*2+bt]
        #pragma unroll
        for (int tile = 0; tile < 2; ++tile) {
            f32x4 acc[2][2];
            #pragma unroll
            for (int q = 0; q < 2; ++q) {
                const float4 bv = *reinterpret_cast<const float4*>(&b2s[w * 32 + q * 16 + lg * 4]);
                f32x4 bi; bi[0] = bv.x; bi[1] = bv.y; bi[2] = bv.z; bi[3] = bv.w;
                acc[q][0] = bi; acc[q][1] = bi;
            }
            #pragma unroll
            for (int kb = 0; kb < 8; ++kb) {
                short8 h0  = *reinterpret_cast<const short8*>(&h[tile * 32 + l15][kb * 32 + lg * 8]);
                short8 h1v = *reinterpret_cast<const short8*>(&h[tile * 32 + 16 + l15][kb * 32 + lg * 8]);
                #pragma unroll
                for (int q = 0; q < 2; ++q) {
                    acc[q][0] = __builtin_amdgcn_mfma_f32_16x16x32_bf16(w2f[q][kb], h0,  acc[q][0], 0, 0, 0);
                    acc[q][1] = __builtin_amdgcn_mfma_f32_16x16x32_bf16(w2f[q][kb], h1v, acc[q][1], 0, 0, 0);
                }
            }
            uint2* pkv = tile ? pkvB : pkvA;
            #pragma unroll
            for (int q = 0; q < 2; ++q)
                #pragma unroll
                for (int bt = 0; bt < 2; ++bt) {
                    pkv[q * 2 + bt].x = pk2(fast_tanh(acc[q][bt][0]), fast_tanh(acc[q][bt][1]));
                    pkv[q * 2 + bt].y = pk2(fast_tanh(acc[q][bt][2]), fast_tanh(acc[q][bt][3]));
                }
        }
        __syncthreads();   // S2a: all h1 reads complete, buffer reusable

        #pragma unroll
        for (int q = 0; q < 2; ++q)
            #pragma unroll
            for (int bt = 0; bt < 2; ++bt) {
                *reinterpret_cast<uint2*>(&h[bt * 16 + l15][w * 32 + q * 16 + lg * 4]) = pkvA[q * 2 + bt];
                *reinterpret_cast<uint2*>(&h[32 + bt * 16 + l15][w * 32 + q * 16 + lg * 4]) = pkvB[q * 2 + bt];
            }
        __syncthreads();   // S2b: h2 ready (both tiles)

        // ---------- P3: d = h2 @ W3 + b3; waves 0,1 -> tile A; 2,3 -> tile B ----------
        if (w < 4) {
            const int b = (w >> 1) * 32 + (w & 1) * 16 + l15;
            f32x4 a3 = {0.f, 0.f, 0.f, 0.f};
            #pragma unroll
            for (int kb = 0; kb < 8; ++kb) {
                short8 hv = *reinterpret_cast<const short8*>(&h[b][kb * 32 + lg * 8]);
                short8 wf = *reinterpret_cast<const short8*>(&w3t[l15][kb * 32 + lg * 8]);
                a3 = __builtin_amdgcn_mfma_f32_16x16x32_bf16(wf, hv, a3, 0, 0, 0);
            }
            const float4 d3 = *reinterpret_cast<const float4*>(&db3[lg * 4]);
            float nsv[4];
            nsv[0] = st[0] + DT_C * a3[0] + d3.x;
            nsv[1] = st[1] + DT_C * a3[1] + d3.y;
            nsv[2] = st[2] + DT_C * a3[2] + d3.z;
            nsv[3] = st[3] + DT_C * a3[3] + d3.w;
            if (lg == 0) {
                // s = 0..3 -> nibf shorts [2..5]
                st[0] = nsv[0]; st[1] = nsv[1]; st[2] = nsv[2]; st[3] = nsv[3];
                *reinterpret_cast<unsigned int*>(&nibf[b][2]) = pk2(nsv[0], nsv[1]);
                *reinterpret_cast<unsigned int*>(&nibf[b][4]) = pk2(nsv[2], nsv[3]);
                const int obase = (b0 + b) * (HS * NS) + t * NS;
                out[obase + 0] = nsv[0];
                out[obase + 1] = nsv[1];
                out[obase + 2] = nsv[2];
                out[obase + 3] = nsv[3];
            } else if (lg == 1) {
                // s = 4..6 -> nibf shorts [6..8]
                st[0] = nsv[0]; st[1] = nsv[1]; st[2] = nsv[2];
                *reinterpret_cast<unsigned int*>(&nibf[b][6]) = pk2(nsv[0], nsv[1]);
                nibf[b][8] = (unsigned short)pk2(nsv[2], nsv[2]);
                const int obase = (b0 + b) * (HS * NS) + t * NS;
                out[obase + 4] = nsv[0];
                out[obase + 5] = nsv[1];
                out[obase + 6] = nsv[2];
            }
        } else if (w == 4) {
            // next-step controls for all 64 rows -> nibf[b][0..1] (bf16)
            if (t + 1 < HS) {
                const int b = lane;
                const float* xp = &x[(b0 + b) * (HS * NF) + (t + 1) * NF];
                nibf[b][0] = f2bf(xp[0]);
                nibf[b][1] = f2bf(xp[1]);
            }
        }
        __syncthreads();   // S3: state/controls ready for next P1
    }
}

extern "C" void kernel_launch(void* const* d_in, const int* in_sizes, int n_in,
                              void* d_out, int out_size, void* d_ws, size_t ws_size,
                              hipStream_t stream) {
    const float* x  = (const float*)d_in[0];
    const float* W1 = (const float*)d_in[1];
    const float* b1 = (const float*)d_in[2];
    const float* W2 = (const float*)d_in[3];
    const float* b2 = (const float*)d_in[4];
    const float* W3 = (const float*)d_in[5];
    const float* b3 = (const float*)d_in[6];
    float* out = (float*)d_out;

    const int B = in_sizes[0] / (HS * NF);   // 32768
    dim3 grid(B / BT), block(512);           // 512 blocks = 2/CU, one round
    hipLaunchKernelGGL(rollout_mfma11, grid, block, 0, stream,
                       x, W1, b1, W2, b2, W3, b3, out);
}